// Round 16
// baseline (3071.678 us; speedup 1.0000x reference)
//
#include <hip/hip_runtime.h>

#define QS 8
#define KC 1024
#define DD 256
#define TT 8192
#define NN 65536
#define TAU 0.06f
#define FLAGCAP 49152
#define PITER_M 12
#define PITER_L 12
#define PITER_O 2

typedef _Float16 half8 __attribute__((ext_vector_type(8)));
typedef float f32x4 __attribute__((ext_vector_type(4)));

// ---------------------------------------------------------------------------
// Encoder: z = conv1d(x) -> res (token-major [N][256]); zero loss + flag cnts.
// ---------------------------------------------------------------------------
__global__ __launch_bounds__(256) void encode_init_kernel(
    const float* __restrict__ x, const float* __restrict__ ew,
    const float* __restrict__ eb, float* __restrict__ res,
    float* __restrict__ lossAcc, int* __restrict__ flagCnt)
{
    if (blockIdx.x == 0 && threadIdx.x == 0) *lossAcc = 0.0f;
    if (blockIdx.x == 0 && threadIdx.x < QS) flagCnt[threadIdx.x] = 0;
    const int d = threadIdx.x;                 // 256 == DD
    const float w0 = ew[d*3 + 0];
    const float w1 = ew[d*3 + 1];
    const float w2 = ew[d*3 + 2];
    const float b  = eb[d];
    #pragma unroll 4
    for (int tt = 0; tt < 16; ++tt) {
        const long n = (long)blockIdx.x * 16 + tt;   // grid = 4096
        const int t = (int)(n & (TT - 1));
        const float xm = (t > 0)      ? x[n - 1] : 0.0f;
        const float x0 = x[n];
        const float xp = (t < TT - 1) ? x[n + 1] : 0.0f;
        res[n * DD + d] = b + w0*xm + w1*x0 + w2*xp;
    }
}

// ---------------------------------------------------------------------------
// c2[s][k] = ||codebook[s][k]||^2 ; writes d_out copy AND d_ws copy (probes).
// ---------------------------------------------------------------------------
__global__ __launch_bounds__(256) void c2_kernel(
    const float* __restrict__ cbs, float* __restrict__ c2,
    float* __restrict__ c2copy)
{
    const int w = (int)((blockIdx.x * blockDim.x + threadIdx.x) >> 6);
    const int lane = threadIdx.x & 63;
    if (w >= QS * KC) return;
    const float* row = cbs + (long)w * DD;
    float s = 0.0f;
    #pragma unroll
    for (int q = 0; q < DD / 64; ++q) {
        const float v = row[lane + 64*q];
        s += v * v;
    }
    #pragma unroll
    for (int off = 32; off; off >>= 1) s += __shfl_down(s, off, 64);
    if (lane == 0) { c2[w] = s; c2copy[w] = s; }
}

// ---------------------------------------------------------------------------
// Per-stage codebook f16, FRAGMENT-LINEAR layout (R15, proven).
// ---------------------------------------------------------------------------
__global__ __launch_bounds__(256) void cb_prep_stage_kernel(
    const float* __restrict__ cb, _Float16* __restrict__ cbh)
{
    const int t = blockIdx.x;          // grid = 64 tiles
    const int cg = t >> 2, kp = t & 3;
    #pragma unroll
    for (int q = 0; q < 2; ++q) {
        const int p = threadIdx.x + 256*q;      // chunk in [0,512)
        const int kc2 = p >> 8, rem = p & 255;
        const int nt = rem >> 6, l4v = (rem >> 4) & 3, l15v = rem & 15;
        const int code = cg*64 + nt*16 + l15v;
        const int k0 = kp*64 + kc2*32 + l4v*8;
        const float* src = &cb[(long)code*DD + k0];
        const float4 v0 = *reinterpret_cast<const float4*>(src);
        const float4 v1 = *reinterpret_cast<const float4*>(src + 4);
        half8 hv;
        hv[0]=(_Float16)v0.x; hv[1]=(_Float16)v0.y;
        hv[2]=(_Float16)v0.z; hv[3]=(_Float16)v0.w;
        hv[4]=(_Float16)v1.x; hv[5]=(_Float16)v1.y;
        hv[6]=(_Float16)v1.z; hv[7]=(_Float16)v1.w;
        *reinterpret_cast<half8*>(
            &cbh[(long)t*4096 + (kc2*4 + nt)*512 + (l4v*16 + l15v)*8]) = hv;
    }
}

// ---------------------------------------------------------------------------
// Fused RVQ stage (R15, proven): f16 MFMA 2-term, B streamed from L2,
// no LDS / no barriers in K-loop, register ping-pong.
// ---------------------------------------------------------------------------
__global__ __launch_bounds__(256, 2) void rvq_pass1_kernel(
    const float* __restrict__ cb,      // [KC][DD] fp32 (epilogue gather)
    const _Float16* __restrict__ cbh,  // [64][4096] f16 fragment-linear
    const float* __restrict__ c2,      // [KC]
    float* __restrict__ res,           // [NN][DD]
    float* __restrict__ lossAcc,
    int* __restrict__ flagCnt,         // this stage
    int* __restrict__ flagList)        // shared list, cap FLAGCAP
{
    __shared__ int idxArr[128];

    const int tid = threadIdx.x;
    const int w   = tid >> 6;
    const int l   = tid & 63;
    const int l15 = l & 15;
    const int l4  = l >> 4;
    const long n0 = (long)blockIdx.x * 128;

    int tr;
    {
        half8 pa, pb;
        #pragma unroll
        for (int e = 0; e < 8; ++e) {
            pa[e] = (_Float16)l15;
            pb[e] = (_Float16)0.03125f;
        }
        f32x4 pacc = (f32x4){0.f, 0.f, 0.f, 0.f};
        pacc = __builtin_amdgcn_mfma_f32_16x16x32_f16(pa, pb, pacc, 0, 0, 0);
        const float p1 = __shfl(pacc[1], 0, 64);
        tr = (p1 < 0.5f) ? 1 : 0;
    }

    half8 ah[2][8], al[2][8];
    #pragma unroll
    for (int mt = 0; mt < 2; ++mt) {
      #pragma unroll
      for (int kc = 0; kc < 8; ++kc) {
        const long n = n0 + w*32 + mt*16 + l15;
        const float* p = &res[n*DD + kc*32 + l4*8];
        const float4 v0 = *reinterpret_cast<const float4*>(p);
        const float4 v1 = *reinterpret_cast<const float4*>(p + 4);
        const float xv[8] = {v0.x, v0.y, v0.z, v0.w, v1.x, v1.y, v1.z, v1.w};
        half8 hv, lv;
        #pragma unroll
        for (int e = 0; e < 8; ++e) {
            const _Float16 hh = (_Float16)xv[e];
            hv[e] = hh;
            lv[e] = (_Float16)(xv[e] - (float)hh);
        }
        ah[mt][kc] = hv; al[mt][kc] = lv;
      }
    }

    float b1[8], b2[8]; int i1[8];
    #pragma unroll
    for (int r = 0; r < 8; ++r) { b1[r] = 1e30f; b2[r] = 1e30f; i1[r] = 0; }

    f32x4 acc[2][4];
    half8 bA[8], bB[8];
    const _Float16* cbhL = cbh + l*8;

    auto loadF = [&](half8* buf, int t) {
        const _Float16* base = cbhL + (long)t*4096;
        #pragma unroll
        for (int f = 0; f < 8; ++f)
            buf[f] = *reinterpret_cast<const half8*>(base + f*512);
    };
    auto comp = [&](const half8* buf, int kp) {
        #pragma unroll
        for (int kc2 = 0; kc2 < 2; ++kc2) {
          const int kc = kp*2 + kc2;
          #pragma unroll
          for (int nt = 0; nt < 4; ++nt) {
            const half8 bh = buf[kc2*4 + nt];
            #pragma unroll
            for (int mt = 0; mt < 2; ++mt) {
              acc[mt][nt] = __builtin_amdgcn_mfma_f32_16x16x32_f16(ah[mt][kc], bh, acc[mt][nt], 0, 0, 0);
              acc[mt][nt] = __builtin_amdgcn_mfma_f32_16x16x32_f16(al[mt][kc], bh, acc[mt][nt], 0, 0, 0);
            }
          }
        }
    };

    loadF(bA, 0);
    for (int cg = 0; cg < 16; ++cg) {
        const int t0 = cg*4;
        #pragma unroll
        for (int mt = 0; mt < 2; ++mt)
            #pragma unroll
            for (int nt = 0; nt < 4; ++nt)
                acc[mt][nt] = (f32x4){0.f, 0.f, 0.f, 0.f};

        loadF(bB, t0 + 1);  comp(bA, 0);
        loadF(bA, t0 + 2);  comp(bB, 1);
        loadF(bB, t0 + 3);  comp(bA, 2);
        if (cg < 15) loadF(bA, t0 + 4);
        comp(bB, 3);

        if (tr == 0) {
            #pragma unroll
            for (int nt = 0; nt < 4; ++nt) {
                const int code = cg*64 + nt*16 + l15;
                const float cc = c2[code];
                #pragma unroll
                for (int mt = 0; mt < 2; ++mt) {
                    #pragma unroll
                    for (int j = 0; j < 4; ++j) {
                        const float dist = cc - 2.0f*acc[mt][nt][j];
                        const int r = mt*4 + j;
                        if (dist < b1[r])      { b2[r] = b1[r]; b1[r] = dist; i1[r] = code; }
                        else if (dist < b2[r]) { b2[r] = dist; }
                    }
                }
            }
        } else {
            #pragma unroll
            for (int nt = 0; nt < 4; ++nt) {
                #pragma unroll
                for (int j = 0; j < 4; ++j) {
                    const int code = cg*64 + nt*16 + l4*4 + j;
                    const float cc = c2[code];
                    #pragma unroll
                    for (int mt = 0; mt < 2; ++mt) {
                        const float dist = cc - 2.0f*acc[mt][nt][j];
                        if (dist < b1[mt])      { b2[mt] = b1[mt]; b1[mt] = dist; i1[mt] = code; }
                        else if (dist < b2[mt]) { b2[mt] = dist; }
                    }
                }
            }
        }
    }

    if (tr == 0) {
      #pragma unroll
      for (int m = 1; m < 16; m <<= 1) {
        #pragma unroll
        for (int r = 0; r < 8; ++r) {
          const float ob1 = __shfl_xor(b1[r], m, 64);
          const float ob2 = __shfl_xor(b2[r], m, 64);
          const int   oi1 = __shfl_xor(i1[r], m, 64);
          const float nb2 = fminf(fminf(b2[r], ob2), fmaxf(b1[r], ob1));
          if (ob1 < b1[r] || (ob1 == b1[r] && oi1 < i1[r])) { b1[r] = ob1; i1[r] = oi1; }
          b2[r] = nb2;
        }
      }
      if (l15 == 0) {
        #pragma unroll
        for (int mt = 0; mt < 2; ++mt)
          #pragma unroll
          for (int j = 0; j < 4; ++j) {
            const int r = mt*4 + j;
            const int row = w*32 + mt*16 + l4*4 + j;
            idxArr[row] = i1[r];
            if (b2[r] - b1[r] < TAU) {
              const int pos = atomicAdd(flagCnt, 1);
              if (pos < FLAGCAP)
                flagList[pos] = (int)(((n0 + row) << 10) | (unsigned)i1[r]);
            }
          }
      }
    } else {
      #pragma unroll
      for (int m = 16; m <= 32; m <<= 1) {
        #pragma unroll
        for (int r = 0; r < 2; ++r) {
          const float ob1 = __shfl_xor(b1[r], m, 64);
          const float ob2 = __shfl_xor(b2[r], m, 64);
          const int   oi1 = __shfl_xor(i1[r], m, 64);
          const float nb2 = fminf(fminf(b2[r], ob2), fmaxf(b1[r], ob1));
          if (ob1 < b1[r] || (ob1 == b1[r] && oi1 < i1[r])) { b1[r] = ob1; i1[r] = oi1; }
          b2[r] = nb2;
        }
      }
      if (l4 == 0) {
        #pragma unroll
        for (int mt = 0; mt < 2; ++mt) {
          const int row = w*32 + mt*16 + l15;
          idxArr[row] = i1[mt];
          if (b2[mt] - b1[mt] < TAU) {
            const int pos = atomicAdd(flagCnt, 1);
            if (pos < FLAGCAP)
              flagList[pos] = (int)(((n0 + row) << 10) | (unsigned)i1[mt]);
          }
        }
      }
    }
    __syncthreads();

    float lsum = 0.0f;
    const int rw = tid >> 6;
    const int cc4 = (tid & 63) * 4;
    #pragma unroll 4
    for (int it = 0; it < 32; ++it) {
        const int r = it*4 + rw;
        const long n = n0 + r;
        const int ix = idxArr[r];
        float4 rv = *reinterpret_cast<const float4*>(&res[n*DD + cc4]);
        const float4 cv = *reinterpret_cast<const float4*>(&cb[(long)ix*DD + cc4]);
        rv.x -= cv.x; rv.y -= cv.y; rv.z -= cv.z; rv.w -= cv.w;
        *reinterpret_cast<float4*>(&res[n*DD + cc4]) = rv;
        lsum += rv.x*rv.x + rv.y*rv.y + rv.z*rv.z + rv.w*rv.w;
    }
    #pragma unroll
    for (int off = 32; off; off >>= 1) lsum += __shfl_down(lsum, off, 64);
    if (l == 0) atomicAdd(lossAcc, lsum);
}

// ---------------------------------------------------------------------------
// Exact fp32 recheck for margin-flagged tokens (unchanged).
// ---------------------------------------------------------------------------
__global__ __launch_bounds__(256) void recheck_kernel(
    const float* __restrict__ cb, const float* __restrict__ c2,
    float* __restrict__ res, float* __restrict__ lossAcc,
    const int* __restrict__ flagCnt, const int* __restrict__ flagList)
{
    __shared__ float rorig[DD];
    __shared__ float sD[256];
    __shared__ int   sI[256];
    const int cnt = min(*flagCnt, FLAGCAP);
    const int tid = threadIdx.x;
    for (int f = blockIdx.x; f < cnt; f += gridDim.x) {
        const int packed = flagList[f];
        const long n  = packed >> 10;
        const int old = packed & 1023;
        __syncthreads();
        const float rme = res[n*DD + tid] + cb[(long)old*DD + tid];
        rorig[tid] = rme;
        __syncthreads();
        float bd = 1e30f; int bi = 0;
        #pragma unroll
        for (int q = 0; q < 4; ++q) {
            const int code = tid + 256*q;
            const float* crow = &cb[(long)code*DD];
            float dot = 0.f;
            for (int d = 0; d < DD; ++d) dot += rorig[d]*crow[d];
            const float dist = c2[code] - 2.0f*dot;
            if (dist < bd || (dist == bd && code < bi)) { bd = dist; bi = code; }
        }
        sD[tid] = bd; sI[tid] = bi;
        __syncthreads();
        for (int s = 128; s; s >>= 1) {
            if (tid < s) {
                const float d2 = sD[tid + s]; const int i2 = sI[tid + s];
                if (d2 < sD[tid] || (d2 == sD[tid] && i2 < sI[tid])) { sD[tid] = d2; sI[tid] = i2; }
            }
            __syncthreads();
        }
        const int best = sI[0];
        if (best != old) {
            const float rn = rorig[tid] - cb[(long)best*DD + tid];
            const float ro = res[n*DD + tid];
            res[n*DD + tid] = rn;
            float delta = rn*rn - ro*ro;
            #pragma unroll
            for (int off = 32; off; off >>= 1) delta += __shfl_down(delta, off, 64);
            if ((tid & 63) == 0) atomicAdd(lossAcc, delta);
        }
    }
}

// ---------------------------------------------------------------------------
// Decoder (unchanged).
// ---------------------------------------------------------------------------
__global__ __launch_bounds__(256) void decode_kernel(
    const float* __restrict__ x,  const float* __restrict__ ew,
    const float* __restrict__ eb, const float* __restrict__ res,
    const float* __restrict__ dw, const float* __restrict__ db,
    const float* __restrict__ lossAcc, float* __restrict__ out)
{
    const long n = (long)blockIdx.x * 4 + (threadIdx.x >> 6);
    const int lane = threadIdx.x & 63;
    const int t = (int)(n & (TT - 1));
    float sum = 0.0f;
    #pragma unroll
    for (int k = 0; k < 3; ++k) {
        const int tm = t + k - 1;
        if (tm < 0 || tm > TT - 1) continue;
        const long m = n + k - 1;
        const float xm = (tm > 0)      ? x[m - 1] : 0.0f;
        const float x0 = x[m];
        const float xp = (tm < TT - 1) ? x[m + 1] : 0.0f;
        #pragma unroll
        for (int q = 0; q < 4; ++q) {
            const int d = lane + 64 * q;
            const float z = eb[d] + ew[d*3]*xm + ew[d*3 + 1]*x0 + ew[d*3 + 2]*xp;
            const float quant = z - res[m * DD + d];
            sum += quant * dw[d*3 + k];
        }
    }
    #pragma unroll
    for (int off = 32; off; off >>= 1) sum += __shfl_down(sum, off, 64);
    if (lane == 0) out[n] = sum + db[0];
    if (blockIdx.x == 0 && threadIdx.x == 0)
        out[NN] = lossAcc[0] * (1.0f / ((float)NN * (float)DD));
}

// ===========================================================================
// DIAGNOSTIC PROBES — run AFTER decode; read cbh/c2copy/res (d_ws), write
// only to sink (d_ws). Anti-DCE: empty asm keep-alives; anti-CSE: opaque
// pointers ("+s") per iteration and "+v" perturbation per cg.
// ===========================================================================

// MFMA+fold only, zero loads in loop. tM = dur / PITER_M per stage-equiv.
__global__ __launch_bounds__(256, 2) void probe_mfma_kernel(
    const _Float16* __restrict__ cbh, const float* __restrict__ c2c,
    float* __restrict__ sink)
{
    const int tid = threadIdx.x;
    const int l   = tid & 63;
    const int l15 = l & 15;
    const int l4  = l >> 4;

    half8 ah[2][8], al[2][8];
    #pragma unroll
    for (int mt = 0; mt < 2; ++mt)
      #pragma unroll
      for (int kc = 0; kc < 8; ++kc)
        #pragma unroll
        for (int e = 0; e < 8; ++e) {
            ah[mt][kc][e] = (_Float16)(0.01f * (float)((l + kc + e) & 15));
            al[mt][kc][e] = (_Float16)(0.001f * (float)((l ^ (kc*8 + e)) & 15));
        }

    half8 bA[8];
    #pragma unroll
    for (int f = 0; f < 8; ++f)
        bA[f] = *reinterpret_cast<const half8*>(cbh + f*512 + l*8);

    float b1[8], b2[8]; int i1[8];
    #pragma unroll
    for (int r = 0; r < 8; ++r) { b1[r] = 1e30f; b2[r] = 1e30f; i1[r] = 0; }

    f32x4 acc[2][4];
    for (int it = 0; it < PITER_M; ++it) {
      for (int cg = 0; cg < 16; ++cg) {
        // anti-CSE: pretend bA changed
        #pragma unroll
        for (int f = 0; f < 8; ++f) {
            int4 u; __builtin_memcpy(&u, &bA[f], 16);
            asm volatile("" : "+v"(u.x), "+v"(u.y), "+v"(u.z), "+v"(u.w));
            __builtin_memcpy(&bA[f], &u, 16);
        }
        #pragma unroll
        for (int mt = 0; mt < 2; ++mt)
            #pragma unroll
            for (int nt = 0; nt < 4; ++nt)
                acc[mt][nt] = (f32x4){0.f, 0.f, 0.f, 0.f};
        #pragma unroll
        for (int kp = 0; kp < 4; ++kp) {
            #pragma unroll
            for (int kc2 = 0; kc2 < 2; ++kc2) {
              const int kc = kp*2 + kc2;
              #pragma unroll
              for (int nt = 0; nt < 4; ++nt) {
                const half8 bh = bA[kc2*4 + nt];
                #pragma unroll
                for (int mt = 0; mt < 2; ++mt) {
                  acc[mt][nt] = __builtin_amdgcn_mfma_f32_16x16x32_f16(ah[mt][kc], bh, acc[mt][nt], 0, 0, 0);
                  acc[mt][nt] = __builtin_amdgcn_mfma_f32_16x16x32_f16(al[mt][kc], bh, acc[mt][nt], 0, 0, 0);
                }
              }
            }
        }
        #pragma unroll
        for (int nt = 0; nt < 4; ++nt) {
            const int code = cg*64 + nt*16 + l15;
            const float cc = c2c[code];
            #pragma unroll
            for (int mt = 0; mt < 2; ++mt) {
                #pragma unroll
                for (int j = 0; j < 4; ++j) {
                    const float dist = cc - 2.0f*acc[mt][nt][j];
                    const int r = mt*4 + j;
                    if (dist < b1[r])      { b2[r] = b1[r]; b1[r] = dist; i1[r] = code; }
                    else if (dist < b2[r]) { b2[r] = dist; }
                }
            }
        }
      }
    }
    float s = 0.f;
    #pragma unroll
    for (int r = 0; r < 8; ++r) s += b1[r] + b2[r] + (float)i1[r];
    if (blockIdx.x == 0 && tid == 0) sink[0] = s;
    asm volatile("" :: "v"(s));
}

// Loads only, zero MFMA. tL = dur / PITER_L per stage-equiv.
__global__ __launch_bounds__(256, 2) void probe_load_kernel(
    const _Float16* __restrict__ cbh)
{
    const int l = threadIdx.x & 63;
    for (int it = 0; it < PITER_L; ++it) {
        long pb = (long)cbh;
        asm volatile("" : "+s"(pb));          // opaque: force re-issue per iter
        const _Float16* base = (const _Float16*)pb + l*8;
        for (int t = 0; t < 64; t += 2) {
            half8 bA[8], bB[8];
            #pragma unroll
            for (int f = 0; f < 8; ++f)
                bA[f] = *reinterpret_cast<const half8*>(base + (long)t*4096 + f*512);
            #pragma unroll
            for (int f = 0; f < 8; ++f)
                bB[f] = *reinterpret_cast<const half8*>(base + (long)(t+1)*4096 + f*512);
            #pragma unroll
            for (int f = 0; f < 8; ++f) {
                int4 u; __builtin_memcpy(&u, &bA[f], 16);
                asm volatile("" :: "v"(u.x), "v"(u.y), "v"(u.z), "v"(u.w));
                __builtin_memcpy(&u, &bB[f], 16);
                asm volatile("" :: "v"(u.x), "v"(u.y), "v"(u.z), "v"(u.w));
            }
        }
    }
}

// Full K-loop + fold at 4 blocks/CU (grid 1024). tO = dur / (2*PITER_O) vs pass1.
__global__ __launch_bounds__(256, 4) void probe_occ_kernel(
    const _Float16* __restrict__ cbh, const float* __restrict__ c2c,
    const float* __restrict__ res, float* __restrict__ sink)
{
    const int tid = threadIdx.x;
    const int w   = tid >> 6;
    const int l   = tid & 63;
    const int l15 = l & 15;
    const int l4  = l >> 4;
    const long n0 = (long)(blockIdx.x & 511) * 128;

    half8 ah[2][8], al[2][8];
    #pragma unroll
    for (int mt = 0; mt < 2; ++mt) {
      #pragma unroll
      for (int kc = 0; kc < 8; ++kc) {
        const long n = n0 + w*32 + mt*16 + l15;
        const float* p = &res[n*DD + kc*32 + l4*8];
        const float4 v0 = *reinterpret_cast<const float4*>(p);
        const float4 v1 = *reinterpret_cast<const float4*>(p + 4);
        const float xv[8] = {v0.x, v0.y, v0.z, v0.w, v1.x, v1.y, v1.z, v1.w};
        half8 hv, lv;
        #pragma unroll
        for (int e = 0; e < 8; ++e) {
            const _Float16 hh = (_Float16)xv[e];
            hv[e] = hh;
            lv[e] = (_Float16)(xv[e] - (float)hh);
        }
        ah[mt][kc] = hv; al[mt][kc] = lv;
      }
    }

    float b1[8], b2[8]; int i1[8];
    #pragma unroll
    for (int r = 0; r < 8; ++r) { b1[r] = 1e30f; b2[r] = 1e30f; i1[r] = 0; }

    f32x4 acc[2][4];
    half8 bA[8], bB[8];

    for (int it = 0; it < PITER_O; ++it) {
        long pb = (long)cbh;
        asm volatile("" : "+s"(pb));
        const _Float16* cbhL = (const _Float16*)pb + l*8;

        auto loadF = [&](half8* buf, int t) {
            const _Float16* base = cbhL + (long)t*4096;
            #pragma unroll
            for (int f = 0; f < 8; ++f)
                buf[f] = *reinterpret_cast<const half8*>(base + f*512);
        };
        auto comp = [&](const half8* buf, int kp) {
            #pragma unroll
            for (int kc2 = 0; kc2 < 2; ++kc2) {
              const int kc = kp*2 + kc2;
              #pragma unroll
              for (int nt = 0; nt < 4; ++nt) {
                const half8 bh = buf[kc2*4 + nt];
                #pragma unroll
                for (int mt = 0; mt < 2; ++mt) {
                  acc[mt][nt] = __builtin_amdgcn_mfma_f32_16x16x32_f16(ah[mt][kc], bh, acc[mt][nt], 0, 0, 0);
                  acc[mt][nt] = __builtin_amdgcn_mfma_f32_16x16x32_f16(al[mt][kc], bh, acc[mt][nt], 0, 0, 0);
                }
              }
            }
        };

        loadF(bA, 0);
        for (int cg = 0; cg < 16; ++cg) {
            const int t0 = cg*4;
            #pragma unroll
            for (int mt = 0; mt < 2; ++mt)
                #pragma unroll
                for (int nt = 0; nt < 4; ++nt)
                    acc[mt][nt] = (f32x4){0.f, 0.f, 0.f, 0.f};

            loadF(bB, t0 + 1);  comp(bA, 0);
            loadF(bA, t0 + 2);  comp(bB, 1);
            loadF(bB, t0 + 3);  comp(bA, 2);
            if (cg < 15) loadF(bA, t0 + 4);
            comp(bB, 3);

            #pragma unroll
            for (int nt = 0; nt < 4; ++nt) {
                const int code = cg*64 + nt*16 + l15;
                const float cc = c2c[code];
                #pragma unroll
                for (int mt = 0; mt < 2; ++mt) {
                    #pragma unroll
                    for (int j = 0; j < 4; ++j) {
                        const float dist = cc - 2.0f*acc[mt][nt][j];
                        const int r = mt*4 + j;
                        if (dist < b1[r])      { b2[r] = b1[r]; b1[r] = dist; i1[r] = code; }
                        else if (dist < b2[r]) { b2[r] = dist; }
                    }
                }
            }
        }
    }
    float s = 0.f;
    #pragma unroll
    for (int r = 0; r < 8; ++r) s += b1[r] + b2[r] + (float)i1[r];
    if (blockIdx.x == 0 && tid == 0) sink[1] = s;
    asm volatile("" :: "v"(s));
}

// ---------------------------------------------------------------------------
// d_ws: res 64MB | lossAcc(4f) | cbh 512KB | c2copy 32KB | sink (~64.6MB tot).
// d_out scratch until decode: flagCnt[8] | c2[8192] | flagList.
// Probes run AFTER decode (read-only on res/cbh/c2copy; write sink only).
// ---------------------------------------------------------------------------
extern "C" void kernel_launch(void* const* d_in, const int* in_sizes, int n_in,
                              void* d_out, int out_size, void* d_ws, size_t ws_size,
                              hipStream_t stream)
{
    const float* x     = (const float*)d_in[0];
    const float* enc_w = (const float*)d_in[1];
    const float* enc_b = (const float*)d_in[2];
    const float* dec_w = (const float*)d_in[3];
    const float* dec_b = (const float*)d_in[4];
    const float* cbs   = (const float*)d_in[5];
    float* out = (float*)d_out;

    float*    res      = (float*)d_ws;
    float*    lossAcc  = res + (size_t)NN * DD;
    _Float16* cbh      = (_Float16*)(lossAcc + 4);      // [64][4096] f16
    float*    c2copy   = (float*)(cbh + 64 * 4096);     // [QS*KC]
    float*    sink     = c2copy + QS * KC;              // scratch
    int*      flagCnt  = (int*)out;
    float*    c2       = out + 8;
    int*      flagList = (int*)(out + 8 + QS * KC);

    hipLaunchKernelGGL(encode_init_kernel, dim3(NN / 16), dim3(256), 0, stream,
                       x, enc_w, enc_b, res, lossAcc, flagCnt);
    hipLaunchKernelGGL(c2_kernel, dim3(QS * KC / 4), dim3(256), 0, stream,
                       cbs, c2, c2copy);
    for (int s = 0; s < QS; ++s) {
        hipLaunchKernelGGL(cb_prep_stage_kernel, dim3(64), dim3(256), 0, stream,
                           cbs + (size_t)s * KC * DD, cbh);
        hipLaunchKernelGGL(rvq_pass1_kernel, dim3(NN / 128), dim3(256), 0, stream,
                           cbs + (size_t)s * KC * DD, cbh,
                           c2 + (size_t)s * KC,
                           res, lossAcc, flagCnt + s, flagList);
        hipLaunchKernelGGL(recheck_kernel, dim3(256), dim3(256), 0, stream,
                           cbs + (size_t)s * KC * DD,
                           c2 + (size_t)s * KC,
                           res, lossAcc, flagCnt + s, flagList);
    }
    hipLaunchKernelGGL(decode_kernel, dim3(NN / 4), dim3(256), 0, stream,
                       x, enc_w, enc_b, res, dec_w, dec_b, lossAcc, out);

    // ---- diagnostics (scratch-only side effects) ----
    hipLaunchKernelGGL(probe_mfma_kernel, dim3(512), dim3(256), 0, stream,
                       cbh, c2copy, sink);
    hipLaunchKernelGGL(probe_load_kernel, dim3(512), dim3(256), 0, stream,
                       cbh);
    hipLaunchKernelGGL(probe_occ_kernel, dim3(1024), dim3(256), 0, stream,
                       cbh, c2copy, res, sink);
}

// Round 17
// 1530.906 us; speedup vs baseline: 2.0064x; 2.0064x over previous
//
#include <hip/hip_runtime.h>

#define QS 8
#define KC 1024
#define DD 256
#define TT 8192
#define NN 65536
#define TAU 0.06f
#define FLAGCAP 49152

typedef _Float16 half8 __attribute__((ext_vector_type(8)));
typedef float f32x4 __attribute__((ext_vector_type(4)));

// ---------------------------------------------------------------------------
// Encoder: z = conv1d(x) -> res (token-major [N][256]); zero loss + flag cnts.
// ---------------------------------------------------------------------------
__global__ __launch_bounds__(256) void encode_init_kernel(
    const float* __restrict__ x, const float* __restrict__ ew,
    const float* __restrict__ eb, float* __restrict__ res,
    float* __restrict__ lossAcc, int* __restrict__ flagCnt)
{
    if (blockIdx.x == 0 && threadIdx.x == 0) *lossAcc = 0.0f;
    if (blockIdx.x == 0 && threadIdx.x < QS) flagCnt[threadIdx.x] = 0;
    const int d = threadIdx.x;                 // 256 == DD
    const float w0 = ew[d*3 + 0];
    const float w1 = ew[d*3 + 1];
    const float w2 = ew[d*3 + 2];
    const float b  = eb[d];
    #pragma unroll 4
    for (int tt = 0; tt < 16; ++tt) {
        const long n = (long)blockIdx.x * 16 + tt;   // grid = 4096
        const int t = (int)(n & (TT - 1));
        const float xm = (t > 0)      ? x[n - 1] : 0.0f;
        const float x0 = x[n];
        const float xp = (t < TT - 1) ? x[n + 1] : 0.0f;
        res[n * DD + d] = b + w0*xm + w1*x0 + w2*xp;
    }
}

// ---------------------------------------------------------------------------
// c2[s][k] = ||codebook[s][k]||^2 ; one wave per code.
// ---------------------------------------------------------------------------
__global__ __launch_bounds__(256) void c2_kernel(
    const float* __restrict__ cbs, float* __restrict__ c2)
{
    const int w = (int)((blockIdx.x * blockDim.x + threadIdx.x) >> 6);
    const int lane = threadIdx.x & 63;
    if (w >= QS * KC) return;
    const float* row = cbs + (long)w * DD;
    float s = 0.0f;
    #pragma unroll
    for (int q = 0; q < DD / 64; ++q) {
        const float v = row[lane + 64*q];
        s += v * v;
    }
    #pragma unroll
    for (int off = 32; off; off >>= 1) s += __shfl_down(s, off, 64);
    if (lane == 0) c2[w] = s;
}

// ---------------------------------------------------------------------------
// Per-stage codebook f16, FRAGMENT-LINEAR layout (R15, proven):
// tile t = cg*4+kp (64 x 4096 f16); fragment f = kc2*4+nt (8 x 512 f16);
// lane l holds 8 f16 at t*4096 + f*512 + l*8.
// ---------------------------------------------------------------------------
__global__ __launch_bounds__(256) void cb_prep_stage_kernel(
    const float* __restrict__ cb, _Float16* __restrict__ cbh)
{
    const int t = blockIdx.x;          // grid = 64 tiles
    const int cg = t >> 2, kp = t & 3;
    #pragma unroll
    for (int q = 0; q < 2; ++q) {
        const int p = threadIdx.x + 256*q;      // chunk in [0,512)
        const int kc2 = p >> 8, rem = p & 255;
        const int nt = rem >> 6, l4v = (rem >> 4) & 3, l15v = rem & 15;
        const int code = cg*64 + nt*16 + l15v;
        const int k0 = kp*64 + kc2*32 + l4v*8;
        const float* src = &cb[(long)code*DD + k0];
        const float4 v0 = *reinterpret_cast<const float4*>(src);
        const float4 v1 = *reinterpret_cast<const float4*>(src + 4);
        half8 hv;
        hv[0]=(_Float16)v0.x; hv[1]=(_Float16)v0.y;
        hv[2]=(_Float16)v0.z; hv[3]=(_Float16)v0.w;
        hv[4]=(_Float16)v1.x; hv[5]=(_Float16)v1.y;
        hv[6]=(_Float16)v1.z; hv[7]=(_Float16)v1.w;
        *reinterpret_cast<half8*>(
            &cbh[(long)t*4096 + (kc2*4 + nt)*512 + (l4v*16 + l15v)*8]) = hv;
    }
}

// ---------------------------------------------------------------------------
// Fused RVQ stage — TLP version: 512 threads (8 waves), 2 blocks/CU ->
// 4 waves/SIMD. Wave owns 16 tokens (1 M-tile). B streamed from L2,
// single-buffered 4-fragment granularity; latency hidden by TLP, not ILP.
// Lean fold (min/max/cndmask). No LDS/barriers in K-loop.
// ---------------------------------------------------------------------------
__global__ __launch_bounds__(512, 4) void rvq_pass1_kernel(
    const float* __restrict__ cb,      // [KC][DD] fp32 (epilogue gather)
    const _Float16* __restrict__ cbh,  // [64][4096] f16 fragment-linear
    const float* __restrict__ c2,      // [KC]
    float* __restrict__ res,           // [NN][DD]
    float* __restrict__ lossAcc,
    int* __restrict__ flagCnt,         // this stage
    int* __restrict__ flagList)        // shared list, cap FLAGCAP
{
    __shared__ int idxArr[128];

    const int tid = threadIdx.x;
    const int w   = tid >> 6;          // 0..7
    const int l   = tid & 63;
    const int l15 = l & 15;
    const int l4  = l >> 4;
    const long n0 = (long)blockIdx.x * 128;
    const long n  = n0 + w*16 + l15;   // this lane's token

    // ---- orientation probe (exact arithmetic; proven rounds 5-15) ----
    int tr;
    {
        half8 pa, pb;
        #pragma unroll
        for (int e = 0; e < 8; ++e) {
            pa[e] = (_Float16)l15;
            pb[e] = (_Float16)0.03125f;
        }
        f32x4 pacc = (f32x4){0.f, 0.f, 0.f, 0.f};
        pacc = __builtin_amdgcn_mfma_f32_16x16x32_f16(pa, pb, pacc, 0, 0, 0);
        const float p1 = __shfl(pacc[1], 0, 64);
        tr = (p1 < 0.5f) ? 1 : 0;
    }

    // ---- A fragments: 1 M-tile, k-run (l>>4)*8 ----
    half8 ah[8], al[8];
    #pragma unroll
    for (int kc = 0; kc < 8; ++kc) {
        const float* p = &res[n*DD + kc*32 + l4*8];
        const float4 v0 = *reinterpret_cast<const float4*>(p);
        const float4 v1 = *reinterpret_cast<const float4*>(p + 4);
        const float xv[8] = {v0.x, v0.y, v0.z, v0.w, v1.x, v1.y, v1.z, v1.w};
        half8 hv, lv;
        #pragma unroll
        for (int e = 0; e < 8; ++e) {
            const _Float16 hh = (_Float16)xv[e];
            hv[e] = hh;
            lv[e] = (_Float16)(xv[e] - (float)hh);
        }
        ah[kc] = hv; al[kc] = lv;
    }

    float b1[4], b2[4]; int i1[4];
    #pragma unroll
    for (int r = 0; r < 4; ++r) { b1[r] = 1e30f; b2[r] = 1e30f; i1[r] = 0; }

    f32x4 acc[4];
    half8 bA[4];
    const _Float16* cbhL = cbh + l*8;

    for (int cg = 0; cg < 16; ++cg) {
        #pragma unroll
        for (int nt = 0; nt < 4; ++nt) acc[nt] = (f32x4){0.f, 0.f, 0.f, 0.f};

        for (int kp = 0; kp < 4; ++kp) {
            const _Float16* base = cbhL + (long)(cg*4 + kp)*4096;
            #pragma unroll
            for (int kc2 = 0; kc2 < 2; ++kc2) {
                const int kc = kp*2 + kc2;
                #pragma unroll
                for (int f = 0; f < 4; ++f)
                    bA[f] = *reinterpret_cast<const half8*>(base + (kc2*4 + f)*512);
                #pragma unroll
                for (int nt = 0; nt < 4; ++nt) {
                    acc[nt] = __builtin_amdgcn_mfma_f32_16x16x32_f16(ah[kc], bA[nt], acc[nt], 0, 0, 0);
                    acc[nt] = __builtin_amdgcn_mfma_f32_16x16x32_f16(al[kc], bA[nt], acc[nt], 0, 0, 0);
                }
            }
        }

        if (tr == 0) {
            // token on reg side (row=l4*4+j), code on lane side (col=l15)
            #pragma unroll
            for (int nt = 0; nt < 4; ++nt) {
                const int code = cg*64 + nt*16 + l15;
                const float cc = c2[code];
                #pragma unroll
                for (int j = 0; j < 4; ++j) {
                    const float dist = fmaf(-2.0f, acc[nt][j], cc);
                    const bool lt = dist < b1[j];
                    b2[j] = fminf(b2[j], fmaxf(b1[j], dist));
                    b1[j] = lt ? dist : b1[j];
                    i1[j] = lt ? code : i1[j];
                }
            }
        } else {
            // token on lane side (l15), code on reg side (l4*4+j)
            #pragma unroll
            for (int nt = 0; nt < 4; ++nt) {
                #pragma unroll
                for (int j = 0; j < 4; ++j) {
                    const int code = cg*64 + nt*16 + l4*4 + j;
                    const float dist = fmaf(-2.0f, acc[nt][j], c2[code]);
                    const bool lt = dist < b1[0];
                    b2[0] = fminf(b2[0], fmaxf(b1[0], dist));
                    b1[0] = lt ? dist : b1[0];
                    i1[0] = lt ? code : i1[0];
                }
            }
        }
    }

    if (tr == 0) {
      // reduce over the 16 code-lanes (l&15): masks 1,2,4,8
      #pragma unroll
      for (int m = 1; m < 16; m <<= 1) {
        #pragma unroll
        for (int r = 0; r < 4; ++r) {
          const float ob1 = __shfl_xor(b1[r], m, 64);
          const float ob2 = __shfl_xor(b2[r], m, 64);
          const int   oi1 = __shfl_xor(i1[r], m, 64);
          const float nb2 = fminf(fminf(b2[r], ob2), fmaxf(b1[r], ob1));
          if (ob1 < b1[r] || (ob1 == b1[r] && oi1 < i1[r])) { b1[r] = ob1; i1[r] = oi1; }
          b2[r] = nb2;
        }
      }
      if (l15 == 0) {
        #pragma unroll
        for (int j = 0; j < 4; ++j) {
          const int row = w*16 + l4*4 + j;
          idxArr[row] = i1[j];
          if (b2[j] - b1[j] < TAU) {
            const int pos = atomicAdd(flagCnt, 1);
            if (pos < FLAGCAP)
              flagList[pos] = (int)(((n0 + row) << 10) | (unsigned)i1[j]);
          }
        }
      }
    } else {
      // reduce over the 4 l4-lanes (same l15): masks 16,32
      #pragma unroll
      for (int m = 16; m <= 32; m <<= 1) {
        const float ob1 = __shfl_xor(b1[0], m, 64);
        const float ob2 = __shfl_xor(b2[0], m, 64);
        const int   oi1 = __shfl_xor(i1[0], m, 64);
        const float nb2 = fminf(fminf(b2[0], ob2), fmaxf(b1[0], ob1));
        if (ob1 < b1[0] || (ob1 == b1[0] && oi1 < i1[0])) { b1[0] = ob1; i1[0] = oi1; }
        b2[0] = nb2;
      }
      if (l4 == 0) {
        const int row = w*16 + l15;
        idxArr[row] = i1[0];
        if (b2[0] - b1[0] < TAU) {
          const int pos = atomicAdd(flagCnt, 1);
          if (pos < FLAGCAP)
            flagList[pos] = (int)(((n0 + row) << 10) | (unsigned)i1[0]);
        }
      }
    }
    __syncthreads();   // idxArr visible (only block barrier in kernel)

    // residual update in place + commitment-loss partial (float4 vectorized:
    // 8 rows/iter, thread t -> row it*8+(t>>6), cols (t&63)*4..+3)
    float lsum = 0.0f;
    const int rw = tid >> 6;        // 0..7
    const int cc4 = (tid & 63) * 4;
    #pragma unroll 4
    for (int it = 0; it < 16; ++it) {
        const int r = it*8 + rw;
        const long nn2 = n0 + r;
        const int ix = idxArr[r];
        float4 rv = *reinterpret_cast<const float4*>(&res[nn2*DD + cc4]);
        const float4 cv = *reinterpret_cast<const float4*>(&cb[(long)ix*DD + cc4]);
        rv.x -= cv.x; rv.y -= cv.y; rv.z -= cv.z; rv.w -= cv.w;
        *reinterpret_cast<float4*>(&res[nn2*DD + cc4]) = rv;
        lsum += rv.x*rv.x + rv.y*rv.y + rv.z*rv.z + rv.w*rv.w;
    }
    #pragma unroll
    for (int off = 32; off; off >>= 1) lsum += __shfl_down(lsum, off, 64);
    if (l == 0) atomicAdd(lossAcc, lsum);
}

// ---------------------------------------------------------------------------
// Exact fp32 recheck for margin-flagged tokens. Fixed grid, grid-strided.
// ---------------------------------------------------------------------------
__global__ __launch_bounds__(256) void recheck_kernel(
    const float* __restrict__ cb, const float* __restrict__ c2,
    float* __restrict__ res, float* __restrict__ lossAcc,
    const int* __restrict__ flagCnt, const int* __restrict__ flagList)
{
    __shared__ float rorig[DD];
    __shared__ float sD[256];
    __shared__ int   sI[256];
    const int cnt = min(*flagCnt, FLAGCAP);
    const int tid = threadIdx.x;
    for (int f = blockIdx.x; f < cnt; f += gridDim.x) {
        const int packed = flagList[f];
        const long n  = packed >> 10;
        const int old = packed & 1023;
        __syncthreads();
        const float rme = res[n*DD + tid] + cb[(long)old*DD + tid];
        rorig[tid] = rme;
        __syncthreads();
        float bd = 1e30f; int bi = 0;
        #pragma unroll
        for (int q = 0; q < 4; ++q) {
            const int code = tid + 256*q;
            const float* crow = &cb[(long)code*DD];
            float dot = 0.f;
            for (int d = 0; d < DD; ++d) dot += rorig[d]*crow[d];
            const float dist = c2[code] - 2.0f*dot;
            if (dist < bd || (dist == bd && code < bi)) { bd = dist; bi = code; }
        }
        sD[tid] = bd; sI[tid] = bi;
        __syncthreads();
        for (int s = 128; s; s >>= 1) {
            if (tid < s) {
                const float d2 = sD[tid + s]; const int i2 = sI[tid + s];
                if (d2 < sD[tid] || (d2 == sD[tid] && i2 < sI[tid])) { sD[tid] = d2; sI[tid] = i2; }
            }
            __syncthreads();
        }
        const int best = sI[0];
        if (best != old) {
            const float rn = rorig[tid] - cb[(long)best*DD + tid];
            const float ro = res[n*DD + tid];
            res[n*DD + tid] = rn;
            float delta = rn*rn - ro*ro;
            #pragma unroll
            for (int off = 32; off; off >>= 1) delta += __shfl_down(delta, off, 64);
            if ((tid & 63) == 0) atomicAdd(lossAcc, delta);
        }
    }
}

// ---------------------------------------------------------------------------
// Decoder: quant = z - res_final (z recomputed); conv1d to 1 channel + loss out.
// ---------------------------------------------------------------------------
__global__ __launch_bounds__(256) void decode_kernel(
    const float* __restrict__ x,  const float* __restrict__ ew,
    const float* __restrict__ eb, const float* __restrict__ res,
    const float* __restrict__ dw, const float* __restrict__ db,
    const float* __restrict__ lossAcc, float* __restrict__ out)
{
    const long n = (long)blockIdx.x * 4 + (threadIdx.x >> 6);
    const int lane = threadIdx.x & 63;
    const int t = (int)(n & (TT - 1));
    float sum = 0.0f;
    #pragma unroll
    for (int k = 0; k < 3; ++k) {
        const int tm = t + k - 1;
        if (tm < 0 || tm > TT - 1) continue;
        const long m = n + k - 1;
        const float xm = (tm > 0)      ? x[m - 1] : 0.0f;
        const float x0 = x[m];
        const float xp = (tm < TT - 1) ? x[m + 1] : 0.0f;
        #pragma unroll
        for (int q = 0; q < 4; ++q) {
            const int d = lane + 64 * q;
            const float z = eb[d] + ew[d*3]*xm + ew[d*3 + 1]*x0 + ew[d*3 + 2]*xp;
            const float quant = z - res[m * DD + d];
            sum += quant * dw[d*3 + k];
        }
    }
    #pragma unroll
    for (int off = 32; off; off >>= 1) sum += __shfl_down(sum, off, 64);
    if (lane == 0) out[n] = sum + db[0];
    if (blockIdx.x == 0 && threadIdx.x == 0)
        out[NN] = lossAcc[0] * (1.0f / ((float)NN * (float)DD));
}

// ---------------------------------------------------------------------------
// Workspace: d_ws = res 64MB + lossAcc(16B) + per-stage cbh 512KB (~64.5MB).
// d_out scratch until decode: [0..7]=flagCnt[8], [8..8199]=c2, [8200..]=flagList.
// ---------------------------------------------------------------------------
extern "C" void kernel_launch(void* const* d_in, const int* in_sizes, int n_in,
                              void* d_out, int out_size, void* d_ws, size_t ws_size,
                              hipStream_t stream)
{
    const float* x     = (const float*)d_in[0];
    const float* enc_w = (const float*)d_in[1];
    const float* enc_b = (const float*)d_in[2];
    const float* dec_w = (const float*)d_in[3];
    const float* dec_b = (const float*)d_in[4];
    const float* cbs   = (const float*)d_in[5];
    float* out = (float*)d_out;

    float*    res      = (float*)d_ws;               // [NN][DD] = 64 MB
    float*    lossAcc  = res + (size_t)NN * DD;      // 1 float (+pad)
    _Float16* cbh      = (_Float16*)(lossAcc + 4);   // [64][4096] f16 = 512 KB
    int*      flagCnt  = (int*)out;                  // [QS] in d_out
    float*    c2       = out + 8;                    // [QS*KC] in d_out
    int*      flagList = (int*)(out + 8 + QS * KC);  // cap FLAGCAP in d_out

    hipLaunchKernelGGL(encode_init_kernel, dim3(NN / 16), dim3(256), 0, stream,
                       x, enc_w, enc_b, res, lossAcc, flagCnt);
    hipLaunchKernelGGL(c2_kernel, dim3(QS * KC / 4), dim3(256), 0, stream,
                       cbs, c2);
    for (int s = 0; s < QS; ++s) {
        hipLaunchKernelGGL(cb_prep_stage_kernel, dim3(64), dim3(256), 0, stream,
                           cbs + (size_t)s * KC * DD, cbh);
        hipLaunchKernelGGL(rvq_pass1_kernel, dim3(NN / 128), dim3(512), 0, stream,
                           cbs + (size_t)s * KC * DD, cbh,
                           c2 + (size_t)s * KC,
                           res, lossAcc, flagCnt + s, flagList);
        hipLaunchKernelGGL(recheck_kernel, dim3(256), dim3(256), 0, stream,
                           cbs + (size_t)s * KC * DD,
                           c2 + (size_t)s * KC,
                           res, lossAcc, flagCnt + s, flagList);
    }
    hipLaunchKernelGGL(decode_kernel, dim3(NN / 4), dim3(256), 0, stream,
                       x, enc_w, enc_b, res, dec_w, dec_b, lossAcc, out);
}

// Round 18
// 1456.607 us; speedup vs baseline: 2.1088x; 1.0510x over previous
//
#include <hip/hip_runtime.h>

#define QS 8
#define KC 1024
#define DD 256
#define TT 8192
#define NN 65536
#define TAU 0.06f

typedef _Float16 half8 __attribute__((ext_vector_type(8)));
typedef float f32x4 __attribute__((ext_vector_type(4)));

// ---------------------------------------------------------------------------
// All-stage codebook prep, FRAGMENT-LINEAR (R15/R17 proven layout), per stage:
// tile t = cg*4+kp; fragment f = kc2*4+nt; lane l slot at t*4096 + f*512 + l*8.
// ---------------------------------------------------------------------------
__global__ __launch_bounds__(256) void cb_prep_all_kernel(
    const float* __restrict__ cbs, _Float16* __restrict__ cbh)
{
    const int b = blockIdx.x, s = b >> 6, t = b & 63;   // grid = QS*64
    const int cg = t >> 2, kp = t & 3;
    const float* cb = cbs + (size_t)s * KC * DD;
    _Float16* dst = cbh + (size_t)s * KC * DD + (size_t)t * 4096;
    #pragma unroll
    for (int q = 0; q < 2; ++q) {
        const int p = threadIdx.x + 256*q;      // chunk in [0,512)
        const int kc2 = p >> 8, rem = p & 255;
        const int nt = rem >> 6, l4v = (rem >> 4) & 3, l15v = rem & 15;
        const int code = cg*64 + nt*16 + l15v;
        const int k0 = kp*64 + kc2*32 + l4v*8;
        const float* src = &cb[(long)code*DD + k0];
        const float4 v0 = *reinterpret_cast<const float4*>(src);
        const float4 v1 = *reinterpret_cast<const float4*>(src + 4);
        half8 hv;
        hv[0]=(_Float16)v0.x; hv[1]=(_Float16)v0.y;
        hv[2]=(_Float16)v0.z; hv[3]=(_Float16)v0.w;
        hv[4]=(_Float16)v1.x; hv[5]=(_Float16)v1.y;
        hv[6]=(_Float16)v1.z; hv[7]=(_Float16)v1.w;
        *reinterpret_cast<half8*>(
            &dst[(kc2*4 + nt)*512 + (l4v*16 + l15v)*8]) = hv;
    }
}

// ---------------------------------------------------------------------------
// c2[s][k] = ||codebook[s][k]||^2 ; also zeroes lossAcc (before mega).
// ---------------------------------------------------------------------------
__global__ __launch_bounds__(256) void c2_kernel(
    const float* __restrict__ cbs, float* __restrict__ c2,
    float* __restrict__ lossAcc)
{
    if (blockIdx.x == 0 && threadIdx.x == 0) *lossAcc = 0.0f;
    const int w = (int)((blockIdx.x * blockDim.x + threadIdx.x) >> 6);
    const int lane = threadIdx.x & 63;
    if (w >= QS * KC) return;
    const float* row = cbs + (long)w * DD;
    float s = 0.0f;
    #pragma unroll
    for (int q = 0; q < DD / 64; ++q) {
        const float v = row[lane + 64*q];
        s += v * v;
    }
    #pragma unroll
    for (int off = 32; off; off >>= 1) s += __shfl_down(s, off, 64);
    if (lane == 0) c2[w] = s;
}

// ---------------------------------------------------------------------------
// MEGA v2: encode + 8 fused RVQ stages. 512 thr (8 waves), wave owns 16
// tokens, 2 blocks/CU (4 waves/SIMD). Residual lives in registers as f16
// hi/lo pairs ah/al (64 VGPR; hi+lo ~= fp32 to 2^-22). Per stage:
//   streaming barrier-free K-loop (R17) -> fold -> barriered flags ->
//   inline exact fp32 recheck (rrow = ah+al broadcast) -> reg update+resplit.
// Zero inter-stage HBM traffic. Final residual stored f16 for decode.
// ---------------------------------------------------------------------------
__global__ __launch_bounds__(512, 4) void mega_kernel(
    const float* __restrict__ x,   const float* __restrict__ ew,
    const float* __restrict__ eb,  const float* __restrict__ cbs,
    const _Float16* __restrict__ cbh, const float* __restrict__ c2all,
    _Float16* __restrict__ resf,   float* __restrict__ lossAcc)
{
    __shared__ int   idxArr[128];
    __shared__ float rrow[DD];
    __shared__ float sD8[8];
    __shared__ int   sI8[8];
    __shared__ int   flagRows[128];
    __shared__ int   flagCnt;

    const int tid = threadIdx.x;
    const int w   = tid >> 6;          // 0..7
    const int l   = tid & 63;
    const int l15 = l & 15;
    const int l4  = l >> 4;
    const int n0  = blockIdx.x * 128;
    const int n   = n0 + w*16 + l15;   // this lane's token

    // ---- orientation probe (exact; proven rounds 5-17) ----
    int tr;
    {
        half8 pa, pb;
        #pragma unroll
        for (int e = 0; e < 8; ++e) {
            pa[e] = (_Float16)l15;
            pb[e] = (_Float16)0.03125f;
        }
        f32x4 pacc = (f32x4){0.f, 0.f, 0.f, 0.f};
        pacc = __builtin_amdgcn_mfma_f32_16x16x32_f16(pa, pb, pacc, 0, 0, 0);
        const float p1 = __shfl(pacc[1], 0, 64);
        tr = (p1 < 0.5f) ? 1 : 0;
    }

    // ---- fused encoder -> ah/al state ----
    half8 ah[8], al[8];
    {
        const int t = n & (TT - 1);
        const float xm = (t > 0)      ? x[n - 1] : 0.0f;
        const float x0v = x[n];
        const float xp = (t < TT - 1) ? x[n + 1] : 0.0f;
        #pragma unroll
        for (int kc = 0; kc < 8; ++kc) {
            #pragma unroll
            for (int e = 0; e < 8; ++e) {
                const int d = kc*32 + l4*8 + e;
                const float z = eb[d] + ew[3*d]*xm + ew[3*d+1]*x0v + ew[3*d+2]*xp;
                const _Float16 hh = (_Float16)z;
                ah[kc][e] = hh;
                al[kc][e] = (_Float16)(z - (float)hh);
            }
        }
    }

    float lsum = 0.0f;

    for (int s = 0; s < QS; ++s) {
        const _Float16* cbhL = cbh + (size_t)s * KC * DD + l*8;
        const float*    cbS  = cbs + (size_t)s * KC * DD;
        const float*    c2S  = c2all + s * KC;

        float b1[4], b2[4]; int i1[4];
        #pragma unroll
        for (int r = 0; r < 4; ++r) { b1[r] = 1e30f; b2[r] = 1e30f; i1[r] = 0; }

        f32x4 acc[4];
        half8 bA[4];

        for (int cg = 0; cg < 16; ++cg) {
            #pragma unroll
            for (int nt = 0; nt < 4; ++nt) acc[nt] = (f32x4){0.f,0.f,0.f,0.f};

            for (int kp = 0; kp < 4; ++kp) {
                const _Float16* base = cbhL + (long)(cg*4 + kp)*4096;
                #pragma unroll
                for (int kc2 = 0; kc2 < 2; ++kc2) {
                    const int kc = kp*2 + kc2;
                    #pragma unroll
                    for (int f = 0; f < 4; ++f)
                        bA[f] = *reinterpret_cast<const half8*>(base + (kc2*4 + f)*512);
                    #pragma unroll
                    for (int nt = 0; nt < 4; ++nt) {
                        acc[nt] = __builtin_amdgcn_mfma_f32_16x16x32_f16(ah[kc], bA[nt], acc[nt], 0, 0, 0);
                        acc[nt] = __builtin_amdgcn_mfma_f32_16x16x32_f16(al[kc], bA[nt], acc[nt], 0, 0, 0);
                    }
                }
            }

            if (tr == 0) {
                // token on reg side (row=l4*4+j), code on lane side (col=l15)
                #pragma unroll
                for (int nt = 0; nt < 4; ++nt) {
                    const int code = cg*64 + nt*16 + l15;
                    const float cc = c2S[code];
                    #pragma unroll
                    for (int j = 0; j < 4; ++j) {
                        const float dist = fmaf(-2.0f, acc[nt][j], cc);
                        const bool lt = dist < b1[j];
                        b2[j] = fminf(b2[j], fmaxf(b1[j], dist));
                        b1[j] = lt ? dist : b1[j];
                        i1[j] = lt ? code : i1[j];
                    }
                }
            } else {
                // token on lane side (l15), code on reg side (l4*4+j)
                #pragma unroll
                for (int nt = 0; nt < 4; ++nt) {
                    #pragma unroll
                    for (int j = 0; j < 4; ++j) {
                        const int code = cg*64 + nt*16 + l4*4 + j;
                        const float dist = fmaf(-2.0f, acc[nt][j], c2S[code]);
                        const bool lt = dist < b1[0];
                        b2[0] = fminf(b2[0], fmaxf(b1[0], dist));
                        b1[0] = lt ? dist : b1[0];
                        i1[0] = lt ? code : i1[0];
                    }
                }
            }
        }

        // ---- flag-count reset with explicit ordering (fixes R14 race) ----
        __syncthreads();                       // A: everyone done with prev LDS
        if (tid == 0) flagCnt = 0;
        __syncthreads();                       // B: reset visible

        // ---- cross-lane reduce + idxArr + flags ----
        if (tr == 0) {
            #pragma unroll
            for (int m = 1; m < 16; m <<= 1) {
                #pragma unroll
                for (int r = 0; r < 4; ++r) {
                    const float ob1 = __shfl_xor(b1[r], m, 64);
                    const float ob2 = __shfl_xor(b2[r], m, 64);
                    const int   oi1 = __shfl_xor(i1[r], m, 64);
                    const float nb2 = fminf(fminf(b2[r], ob2), fmaxf(b1[r], ob1));
                    if (ob1 < b1[r] || (ob1 == b1[r] && oi1 < i1[r])) { b1[r] = ob1; i1[r] = oi1; }
                    b2[r] = nb2;
                }
            }
            if (l15 == 0) {
                #pragma unroll
                for (int j = 0; j < 4; ++j) {
                    const int row = w*16 + l4*4 + j;
                    idxArr[row] = i1[j];
                    if (b2[j] - b1[j] < TAU) {
                        const int pos = atomicAdd(&flagCnt, 1);
                        flagRows[pos] = row;            // cap 128 = all rows
                    }
                }
            }
        } else {
            #pragma unroll
            for (int m = 16; m <= 32; m <<= 1) {
                const float ob1 = __shfl_xor(b1[0], m, 64);
                const float ob2 = __shfl_xor(b2[0], m, 64);
                const int   oi1 = __shfl_xor(i1[0], m, 64);
                const float nb2 = fminf(fminf(b2[0], ob2), fmaxf(b1[0], ob1));
                if (ob1 < b1[0] || (ob1 == b1[0] && oi1 < i1[0])) { b1[0] = ob1; i1[0] = oi1; }
                b2[0] = nb2;
            }
            if (l4 == 0) {
                const int row = w*16 + l15;
                idxArr[row] = i1[0];
                if (b2[0] - b1[0] < TAU) {
                    const int pos = atomicAdd(&flagCnt, 1);
                    flagRows[pos] = row;
                }
            }
        }
        __syncthreads();                       // C: idxArr + flags visible

        // ---- inline exact recheck (pre-update residual from ah/al) ----
        const int fc = flagCnt;
        for (int f = 0; f < fc; ++f) {
            const int row = flagRows[f];
            if (w == (row >> 4) && l15 == (row & 15)) {
                #pragma unroll
                for (int kc = 0; kc < 8; ++kc)
                    #pragma unroll
                    for (int e = 0; e < 8; ++e)
                        rrow[kc*32 + l4*8 + e] = (float)ah[kc][e] + (float)al[kc][e];
            }
            __syncthreads();
            float bd = 1e30f; int bi = 0;
            #pragma unroll
            for (int q = 0; q < 2; ++q) {
                const int code = tid*2 + q;
                const float* crow = cbS + (size_t)code * DD;
                float dot = 0.f;
                for (int d4 = 0; d4 < DD; d4 += 4) {
                    const float4 cv = *reinterpret_cast<const float4*>(&crow[d4]);
                    dot += rrow[d4]*cv.x + rrow[d4+1]*cv.y
                         + rrow[d4+2]*cv.z + rrow[d4+3]*cv.w;
                }
                const float dist = c2S[code] - 2.0f*dot;
                if (dist < bd || (dist == bd && code < bi)) { bd = dist; bi = code; }
            }
            #pragma unroll
            for (int off = 32; off; off >>= 1) {
                const float od = __shfl_down(bd, off, 64);
                const int   oi = __shfl_down(bi, off, 64);
                if (od < bd || (od == bd && oi < bi)) { bd = od; bi = oi; }
            }
            if (l == 0) { sD8[w] = bd; sI8[w] = bi; }
            __syncthreads();
            if (tid == 0) {
                float fbd = sD8[0]; int fbi = sI8[0];
                #pragma unroll
                for (int ww = 1; ww < 8; ++ww) {
                    if (sD8[ww] < fbd || (sD8[ww] == fbd && sI8[ww] < fbi)) {
                        fbd = sD8[ww]; fbi = sI8[ww];
                    }
                }
                idxArr[row] = fbi;
            }
            __syncthreads();
        }

        // ---- register residual update (fp32 cb gather) + loss + resplit ----
        const int ix = idxArr[w*16 + l15];
        const float* crow = cbS + (size_t)ix * DD;
        #pragma unroll
        for (int kc = 0; kc < 8; ++kc) {
            const float4 c0 = *reinterpret_cast<const float4*>(&crow[kc*32 + l4*8]);
            const float4 c1 = *reinterpret_cast<const float4*>(&crow[kc*32 + l4*8 + 4]);
            const float cv[8] = {c0.x, c0.y, c0.z, c0.w, c1.x, c1.y, c1.z, c1.w};
            #pragma unroll
            for (int e = 0; e < 8; ++e) {
                const float rv = ((float)ah[kc][e] + (float)al[kc][e]) - cv[e];
                lsum += rv * rv;
                const _Float16 hh = (_Float16)rv;
                ah[kc][e] = hh;
                al[kc][e] = (_Float16)(rv - (float)hh);
            }
        }
    }

    // ---- store final residual (f16) for decode + loss ----
    #pragma unroll
    for (int kc = 0; kc < 8; ++kc) {
        half8 hv;
        #pragma unroll
        for (int e = 0; e < 8; ++e)
            hv[e] = (_Float16)((float)ah[kc][e] + (float)al[kc][e]);
        *reinterpret_cast<half8*>(&resf[(size_t)n*DD + kc*32 + l4*8]) = hv;
    }
    #pragma unroll
    for (int off = 32; off; off >>= 1) lsum += __shfl_down(lsum, off, 64);
    if (l == 0) atomicAdd(lossAcc, lsum);
}

// ---------------------------------------------------------------------------
// Decoder: quant = z - res_final (z recomputed; res f16); conv1d + loss out.
// ---------------------------------------------------------------------------
__global__ __launch_bounds__(256) void decode_kernel(
    const float* __restrict__ x,  const float* __restrict__ ew,
    const float* __restrict__ eb, const _Float16* __restrict__ resf,
    const float* __restrict__ dw, const float* __restrict__ db,
    const float* __restrict__ lossAcc, float* __restrict__ out)
{
    const long n = (long)blockIdx.x * 4 + (threadIdx.x >> 6);
    const int lane = threadIdx.x & 63;
    const int t = (int)(n & (TT - 1));
    float sum = 0.0f;
    #pragma unroll
    for (int k = 0; k < 3; ++k) {
        const int tm = t + k - 1;
        if (tm < 0 || tm > TT - 1) continue;
        const long m = n + k - 1;
        const float xm = (tm > 0)      ? x[m - 1] : 0.0f;
        const float x0 = x[m];
        const float xp = (tm < TT - 1) ? x[m + 1] : 0.0f;
        #pragma unroll
        for (int q = 0; q < 4; ++q) {
            const int d = lane + 64 * q;
            const float z = eb[d] + ew[d*3]*xm + ew[d*3 + 1]*x0 + ew[d*3 + 2]*xp;
            const float quant = z - (float)resf[m * DD + d];
            sum += quant * dw[d*3 + k];
        }
    }
    #pragma unroll
    for (int off = 32; off; off >>= 1) sum += __shfl_down(sum, off, 64);
    if (lane == 0) out[n] = sum + db[0];
    if (blockIdx.x == 0 && threadIdx.x == 0)
        out[NN] = lossAcc[0] * (1.0f / ((float)NN * (float)DD));
}

// ---------------------------------------------------------------------------
// Workspace: d_ws = resf16 32MB + cbh 4MB + lossAcc (~36MB, proven-safe).
// d_out scratch until decode: [8..8199] = c2 (consumed by mega before decode).
// ---------------------------------------------------------------------------
extern "C" void kernel_launch(void* const* d_in, const int* in_sizes, int n_in,
                              void* d_out, int out_size, void* d_ws, size_t ws_size,
                              hipStream_t stream)
{
    const float* x     = (const float*)d_in[0];
    const float* enc_w = (const float*)d_in[1];
    const float* enc_b = (const float*)d_in[2];
    const float* dec_w = (const float*)d_in[3];
    const float* dec_b = (const float*)d_in[4];
    const float* cbs   = (const float*)d_in[5];
    float* out = (float*)d_out;

    _Float16* resf    = (_Float16*)d_ws;                 // [NN][DD] f16 = 32 MB
    _Float16* cbh     = resf + (size_t)NN * DD;          // [QS][KC][DD] f16 = 4 MB
    float*    lossAcc = (float*)(cbh + (size_t)QS * KC * DD);
    float*    c2      = out + 8;                         // [QS*KC] in d_out

    hipLaunchKernelGGL(cb_prep_all_kernel, dim3(QS * 64), dim3(256), 0, stream,
                       cbs, cbh);
    hipLaunchKernelGGL(c2_kernel, dim3(QS * KC / 4), dim3(256), 0, stream,
                       cbs, c2, lossAcc);
    hipLaunchKernelGGL(mega_kernel, dim3(NN / 128), dim3(512), 0, stream,
                       x, enc_w, enc_b, cbs, cbh, c2, resf, lossAcc);
    hipLaunchKernelGGL(decode_kernel, dim3(NN / 4), dim3(256), 0, stream,
                       x, enc_w, enc_b, resf, dec_w, dec_b, lossAcc, out);
}